// Round 11
// baseline (187.000 us; speedup 1.0000x reference)
//
#include <hip/hip_runtime.h>
#include <stdint.h>
#include <stddef.h>

// EuclideanAttention MI355X, round 20.
// - flash: 4 independent barrier domains at CONSTANT traffic. 128-thread
//   blocks (2 waves x 32 q-rows, keeps 2-qg K/V reuse), 64 q-rows/block,
//   grid (32,32)=1024, K[2]/V[2] double-buffer -> 40KB LDS -> 4 blocks/CU
//   (same 8 waves/CU as r17, but 4 domains instead of 2). Staging: 8
//   GLD_LDS/chunk for 128 lanes (V XOR rows offset by multiples of 16 ->
//   involution preserved). Body: issue stage(c+1) -> compute(c) -> vmcnt(0)
//   -> barrier (1 body of latency cover). Evidence: r9 (4 domains, 2x
//   traffic)=60.8, r13 (2 domains, 1x)=50, r14 (1 domain)=56; traffic cuts
//   at fixed domains were null -> domains, not traffic, are the lever.
// - GEMMs + prep: identical to r19 (controls).

#define LOG2E 1.44269504088896f

typedef __attribute__((ext_vector_type(8))) short bf16x8;
typedef __attribute__((ext_vector_type(4))) float f32x4;
typedef __attribute__((ext_vector_type(4))) unsigned short u16x4;

__device__ __forceinline__ unsigned short f2b(float f) {
  union { float f; unsigned int u; } x; x.f = f;
  unsigned int u = x.u;
  u += 0x7fffu + ((u >> 16) & 1u);   // RNE
  return (unsigned short)(u >> 16);
}
__device__ __forceinline__ float b2f(unsigned short s) {
  union { unsigned int u; float f; } x; x.u = ((unsigned int)s) << 16;
  return x.f;
}
__device__ __forceinline__ unsigned int fbits(float f) {
  union { float f; unsigned int u; } x; x.f = f; return x.u;
}

// async global->LDS, 16B per lane. LDS dest = wave-uniform base + lane*16.
#define GLD_LDS(g, l) __builtin_amdgcn_global_load_lds( \
    (const __attribute__((address_space(1))) void*)(g), \
    (__attribute__((address_space(3))) void*)(l), 16, 0, 0)

// ------------------------------------------------- prep: W transpose + X cvt
__global__ void prep_kernel(const float* __restrict__ X,
                            const float* __restrict__ wq, const float* __restrict__ wk,
                            const float* __restrict__ wv, const float* __restrict__ wo,
                            unsigned short* __restrict__ Xb,
                            unsigned short* __restrict__ WTqkv, unsigned short* __restrict__ WTo) {
  int z = blockIdx.z;
  if (z == 4) {
    size_t base = ((size_t)(blockIdx.y * 16 + blockIdx.x)) * 16384;
    #pragma unroll
    for (int j = 0; j < 16; ++j) {
      size_t i = base + (size_t)(j * 256 + threadIdx.x) * 4;
      f32x4 v = *(const f32x4*)&X[i];
      u16x4 o;
      #pragma unroll
      for (int k = 0; k < 4; ++k) o[k] = f2b(v[k]);
      *(u16x4*)&Xb[i] = o;
    }
    return;
  }
  __shared__ float tile[64][65];
  const float* src = (z == 0) ? wq : (z == 1) ? wk : (z == 2) ? wv : wo;
  unsigned short* dst = (z < 3) ? (WTqkv + (size_t)z * 1024 * 1024) : WTo;
  int k0 = blockIdx.y * 64, n0 = blockIdx.x * 64;
  int tr = threadIdx.x >> 4;           // 0..15
  int tc4 = (threadIdx.x & 15) * 4;    // 0,4,..,60
  #pragma unroll
  for (int p = 0; p < 4; ++p) {
    int row = p * 16 + tr;
    f32x4 v = *(const f32x4*)&src[(size_t)(k0 + row) * 1024 + n0 + tc4];
    #pragma unroll
    for (int j = 0; j < 4; ++j) tile[row][tc4 + j] = v[j];
  }
  __syncthreads();
  #pragma unroll
  for (int p = 0; p < 4; ++p) {
    int nr = p * 16 + tr;              // n offset
    u16x4 o;
    #pragma unroll
    for (int j = 0; j < 4; ++j) o[j] = f2b(tile[tc4 + j][nr]);
    *(u16x4*)&dst[(size_t)(n0 + nr) * 1024 + k0 + tc4] = o;
  }
}

// -------------------------------------------------------------- QKV GEMM
// C[4096,3072] = X @ [wq|wk|wv] + bias. 128x128 tile, BK=32 half-steps,
// 3-buffer 2-deep pipeline, 1 barrier + vmcnt(4) per half-step, 3 blocks/CU.
// LDS tiles XOR-unit swizzled: unit' = ko ^ (row&3)  (bank 8-way -> 4-way).
__global__ __launch_bounds__(256, 3) void gemm_qkv_kernel(
    const unsigned short* __restrict__ X, const unsigned short* __restrict__ WT,
    const float* __restrict__ bq, const float* __restrict__ bk, const float* __restrict__ bv,
    const float* __restrict__ temp,
    unsigned short* __restrict__ Qb, unsigned short* __restrict__ Kb,
    unsigned short* __restrict__ VTo, float* __restrict__ ks2) {
  __shared__ __align__(16) unsigned short smem3[24576];  // A3(12288) B3(12288) | Vt alias
#define AS3(j) (smem3 + (j) * 4096)
#define BS3(j) (smem3 + 12288 + (j) * 4096)
  const int t = threadIdx.x, w = t >> 6, lane = t & 63;
  const int r = lane & 15, q4 = lane >> 4;
  const int m0 = blockIdx.y * 128, n0 = blockIdx.x * 128;
  const int wr = (w >> 1) * 64, wc = (w & 1) * 64;
  const unsigned short* Xg = X + (size_t)m0 * 1024;
  const unsigned short* Wg = WT + (size_t)n0 * 1024;
  const int swz = ((t & 3) ^ ((t >> 2) & 3)) * 8;
  const unsigned short* xs0 = Xg + (size_t)(t >> 2) * 1024 + swz;
  const unsigned short* xs1 = xs0 + (size_t)64 * 1024;
  const unsigned short* ws0 = Wg + (size_t)(t >> 2) * 1024 + swz;
  const unsigned short* ws1 = ws0 + (size_t)64 * 1024;
  f32x4 acc[4][4] = {};

#define QKV_STAGE(J2)                                     \
  {                                                       \
    GLD_LDS(xs0, &AS3(J2)[(w * 64) * 8]);                 \
    GLD_LDS(xs1, &AS3(J2)[(256 + w * 64) * 8]);           \
    GLD_LDS(ws0, &BS3(J2)[(w * 64) * 8]);                 \
    GLD_LDS(ws1, &BS3(J2)[(256 + w * 64) * 8]);           \
    xs0 += 32; xs1 += 32; ws0 += 32; ws1 += 32;           \
  }

  QKV_STAGE(0)
  QKV_STAGE(1)
  asm volatile("s_waitcnt vmcnt(4)" ::: "memory");
  __builtin_amdgcn_s_barrier();
  __builtin_amdgcn_sched_barrier(0);

  const int ru = (q4 ^ (r & 3)) * 8;    // swizzled read unit offset (bf16 elems)

#define QKV_BODY(J, STG, LAST)                                                \
  {                                                                           \
    if (STG) QKV_STAGE(((J) + 2) % 3)                                         \
    bf16x8 af[4], bfr[4];                                                     \
    _Pragma("unroll")                                                         \
    for (int mf = 0; mf < 4; ++mf)                                            \
      af[mf] = *(const bf16x8*)&AS3(J)[(wr + mf * 16 + r) * 32 + ru];         \
    _Pragma("unroll")                                                         \
    for (int nf = 0; nf < 4; ++nf)                                            \
      bfr[nf] = *(const bf16x8*)&BS3(J)[(wc + nf * 16 + r) * 32 + ru];        \
    _Pragma("unroll")                                                         \
    for (int mf = 0; mf < 4; ++mf)                                            \
      _Pragma("unroll")                                                       \
      for (int nf = 0; nf < 4; ++nf)                                          \
        acc[mf][nf] = __builtin_amdgcn_mfma_f32_16x16x32_bf16(af[mf], bfr[nf], acc[mf][nf], 0, 0, 0); \
    if (STG)       { asm volatile("s_waitcnt vmcnt(4)" ::: "memory"); }       \
    else if (!(LAST)) { asm volatile("s_waitcnt vmcnt(0)" ::: "memory"); }    \
    if (!(LAST)) {                                                            \
      __builtin_amdgcn_s_barrier();                                           \
      __builtin_amdgcn_sched_barrier(0);                                      \
    }                                                                         \
  }

  for (int hh = 0; hh < 5; ++hh) {
    QKV_BODY(0, 1, 0) QKV_BODY(1, 1, 0) QKV_BODY(2, 1, 0)
    QKV_BODY(0, 1, 0) QKV_BODY(1, 1, 0) QKV_BODY(2, 1, 0)
  }
  QKV_BODY(0, 0, 0)
  QKV_BODY(1, 0, 1)
  __syncthreads();
#undef QKV_BODY
#undef QKV_STAGE

  const int nblk = n0 >> 10;
  if (nblk == 0) {
    const int nc0 = n0 & 1023;
    #pragma unroll
    for (int nf = 0; nf < 4; ++nf) {
      int n = nc0 + wc + nf * 16 + r;
      float bb = bq[n];
      #pragma unroll
      for (int mf = 0; mf < 4; ++mf) {
        int m = m0 + wr + mf * 16 + q4 * 4;
        f32x4 v = acc[mf][nf];
        #pragma unroll
        for (int i = 0; i < 4; ++i)
          Qb[(size_t)(m + i) * 1024 + n] = f2b(v[i] + bb);
      }
    }
  } else if (nblk == 1) {
    const float sc = LOG2E / temp[0];
    const int nc0 = n0 & 1023;
    float s2a[4][4] = {};
    #pragma unroll
    for (int nf = 0; nf < 4; ++nf) {
      int n = nc0 + wc + nf * 16 + r;
      float bb = bk[n];
      #pragma unroll
      for (int mf = 0; mf < 4; ++mf) {
        int m = m0 + wr + mf * 16 + q4 * 4;
        f32x4 v = acc[mf][nf];
        #pragma unroll
        for (int i = 0; i < 4; ++i) {
          unsigned short os = f2b(v[i] + bb);
          Kb[(size_t)(m + i) * 1024 + n] = os;
          float xb = b2f(os);
          s2a[mf][i] += xb * xb;          // sum of squares of the ROUNDED value
        }
      }
    }
    #pragma unroll
    for (int mf = 0; mf < 4; ++mf)
      #pragma unroll
      for (int i = 0; i < 4; ++i) {
        float v = s2a[mf][i];
        v += __shfl_xor(v, 1, 64);
        v += __shfl_xor(v, 2, 64);
        v += __shfl_xor(v, 4, 64);
        v += __shfl_xor(v, 8, 64);
        s2a[mf][i] = v * sc;
      }
    if (r == 0) {
      int hh2 = (nc0 + wc) >> 6;
      #pragma unroll
      for (int mf = 0; mf < 4; ++mf) {
        int m = m0 + wr + mf * 16 + q4 * 4;
        int bb2 = m >> 11, ss = m & 2047;
        #pragma unroll
        for (int i = 0; i < 4; ++i)
          ks2[(size_t)(bb2 * 16 + hh2) * 2048 + ss + i] = s2a[mf][i];
      }
    }
  } else {
    unsigned short* Vt = smem3;         // [head<2][d<64][G<2 * pos<64], stride 132
    const int c0 = n0 - 2048;
    const int head = w & 1;
    #pragma unroll
    for (int nf = 0; nf < 4; ++nf) {
      int c = c0 + wc + nf * 16 + r;
      float bb = bv[c];
      int d = c & 63;
      #pragma unroll
      for (int mf = 0; mf < 4; ++mf) {
        int mloc = wr + mf * 16 + q4 * 4;     // 0..124
        int G = mloc >> 6;
        int k6 = mloc & 63;
        int pos = (k6 >> 5) * 32 + ((k6 & 15) >> 2) * 8 + ((k6 >> 4) & 1) * 4;
        f32x4 v = acc[mf][nf];
        u16x4 pk;
        #pragma unroll
        for (int i = 0; i < 4; ++i) pk[i] = f2b(v[i] + bb);
        *(u16x4*)&Vt[(head * 64 + d) * 132 + G * 64 + pos] = pk;
      }
    }
    __syncthreads();
    int row = t >> 1, ch = t & 1;
    int hd = row >> 6, dd = row & 63;
    int hglob = (c0 >> 6) + hd;
    int bb2 = m0 >> 11, s0 = m0 & 2047;
    unsigned short* dst = &VTo[((size_t)((bb2 * 16 + hglob) * 64 + dd)) * 2048 + s0 + ch * 64];
    const unsigned short* srcL = &Vt[(hd * 64 + dd) * 132 + ch * 64];
    #pragma unroll
    for (int k2 = 0; k2 < 16; ++k2)
      *(u16x4*)&dst[k2 * 4] = *(const u16x4*)&srcL[k2 * 4];
  }
#undef AS3
#undef BS3
}

// ---------------------------------------------------------------- flash
// Block = (bh, 64 q-rows), 2 waves x 32 rows (2 qg each). Grid (32,32)=1024
// blocks, XCD-swizzled (bh == wgid mod 8; per-XCD KV 2MB L2-resident).
// K[2]/V[2] double-buffer + KQs = 40KB LDS -> 4 blocks/CU (4 barrier
// domains, 8 waves/CU). Body(c): [c in 1..30: issue stage(c+1), 8 GLD_LDS]
// -> QK(c) -> exp(c) -> PV(c) -> vmcnt(0) -> s_barrier.
// p = exp2((2qk - k^2)*log2e/T)  (q^2 shift cancels; bounded by ~8)
__global__ __launch_bounds__(128, 2) void flash_kernel(
    const unsigned short* __restrict__ Qb, const unsigned short* __restrict__ Kb,
    const unsigned short* __restrict__ VT, const float* __restrict__ ks2,
    const float* __restrict__ temp, unsigned short* __restrict__ AO) {
  __shared__ __align__(16) unsigned short Ks[2][64 * 64];   // [buf][khalf<2][key<64][dd<32]
  __shared__ __align__(16) unsigned short Vs[2][64 * 64];   // [buf] XOR-swizzled 16B units
  __shared__ __align__(16) float KQs[2048];                 // pre-scaled k^2 for this bh
  const int t = threadIdx.x, w = t >> 6, lane = t & 63;     // w in {0,1}
  const int r = lane & 15, q4 = lane >> 4;
  const int wgid = blockIdx.x + 32 * blockIdx.y;   // [0,1024)
  const int xcd = wgid & 7, s = wgid >> 3;         // s in [0,128)
  const int bh = xcd + 8 * (s & 3);                // 4 bh per XCD
  const int b = bh >> 4, h = bh & 15;
  const int q0 = (s >> 2) * 64;                    // 32 q-chunks per bh
  const float cc = 2.0f * LOG2E / temp[0];

  bf16x8 qf[2][2];
  #pragma unroll
  for (int qg = 0; qg < 2; ++qg) {
    int sq = q0 + w * 32 + qg * 16 + r;
    const unsigned short* qp = Qb + (size_t)(b * 2048 + sq) * 1024 + h * 64;
    #pragma unroll
    for (int ks = 0; ks < 2; ++ks) qf[qg][ks] = *(const bf16x8*)(qp + ks * 32 + q4 * 8);
  }

  f32x4 accO[2][4] = {};
  f32x4 lsum[2] = {};
  bf16x8 ones;
  #pragma unroll
  for (int j = 0; j < 8; ++j) ones[j] = (short)0x3F80;   // bf16 1.0

  const unsigned short* Kg = Kb + ((size_t)b * 2048) * 1024 + h * 64;
  const unsigned short* Vg = VT + ((size_t)bh * 64) * 2048;
  const float* kqb = ks2 + bh * 2048;

  // 128-lane staging sources. K: lane t covers khalf{0,1} x rows {t>>2, t>>2+32},
  // 16B at ko=(t&3)*8. V: rows dd {t>>3, +16, +32, +48}, XOR col (t&7)^(dd&7)
  // (row offsets are multiples of 16 -> dd&7 invariant -> same involution).
  const unsigned short* kp0 = Kg + (size_t)(t >> 2) * 1024 + (t & 3) * 8;  // khalf0 rows 0-31
  const unsigned short* kp1 = kp0 + 32;                                    // khalf1 rows 0-31
  int dd0 = t >> 3;                                                        // 0..15
  const unsigned short* vp0 = Vg + (size_t)dd0 * 2048 + ((t & 7) ^ (dd0 & 7)) * 8;

#define STAGE_CHUNK(BUF)                                                      \
  {                                                                           \
    GLD_LDS(kp0,                  &Ks[BUF][t * 8]);                           \
    GLD_LDS(kp0 + 32 * 1024,      &Ks[BUF][(128 + t) * 8]);                   \
    GLD_LDS(kp1,                  &Ks[BUF][(256 + t) * 8]);                   \
    GLD_LDS(kp1 + 32 * 1024,      &Ks[BUF][(384 + t) * 8]);                   \
    GLD_LDS(vp0,                  &Vs[BUF][t * 8]);                           \
    GLD_LDS(vp0 + 16 * 2048,      &Vs[BUF][(128 + t) * 8]);                   \
    GLD_LDS(vp0 + 32 * 2048,      &Vs[BUF][(256 + t) * 8]);                   \
    GLD_LDS(vp0 + 48 * 2048,      &Vs[BUF][(384 + t) * 8]);                   \
    kp0 += 65536; kp1 += 65536; vp0 += 64;                                    \
  }

  // ---- prologue: ks2 -> LDS (4 issues), stage chunk0 -> buf0, chunk1 -> buf1
  GLD_LDS(kqb + t * 4,        &KQs[t * 4]);
  GLD_LDS(kqb + 512 + t * 4,  &KQs[512 + t * 4]);
  GLD_LDS(kqb + 1024 + t * 4, &KQs[1024 + t * 4]);
  GLD_LDS(kqb + 1536 + t * 4, &KQs[1536 + t * 4]);
  STAGE_CHUNK(0)
  STAGE_CHUNK(1)
  // in-flight: qf(4) + kq(4) + st0(8) + st1(8) = 24; drain all but st1.
  asm volatile("s_waitcnt vmcnt(8)" ::: "memory");
  __builtin_amdgcn_s_barrier();
  __builtin_amdgcn_sched_barrier(0);

  // ---- main loop. J = c&1 static per body; stage(c+1) -> buf J^1.
#define CHUNK_BODY(C, J, STG, LAST)                                           \
  {                                                                           \
    const int c_ = (C);                                                       \
    if (STG) STAGE_CHUNK((J) ^ 1)                                             \
    /* QK(c): A=K-frag (m=key), B=Q-frag (n=qrow); 2 MFMAs per K read */      \
    f32x4 st[2][4];                                                           \
    {                                                                         \
      const f32x4 zz = {};                                                    \
      __builtin_amdgcn_s_setprio(1);                                          \
      _Pragma("unroll")                                                       \
      for (int ks = 0; ks < 2; ++ks) {                                        \
        _Pragma("unroll")                                                     \
        for (int kfm = 0; kfm < 4; ++kfm) {                                   \
          bf16x8 ka = *(const bf16x8*)&Ks[(J)][(ks * 64 + kfm * 16 + r) * 32 + q4 * 8]; \
          st[0][kfm] = __builtin_amdgcn_mfma_f32_16x16x32_bf16(ka, qf[0][ks], ks ? st[0][kfm] : zz, 0, 0, 0); \
          st[1][kfm] = __builtin_amdgcn_mfma_f32_16x16x32_bf16(ka, qf[1][ks], ks ? st[1][kfm] : zz, 0, 0, 0); \
        }                                                                     \
      }                                                                       \
      __builtin_amdgcn_s_setprio(0);                                          \
    }                                                                         \
    /* exp(c): p = exp2(cc*qk - k2s); trunc-pack to pf[qg][cb] */             \
    f32x4 kq[4];                                                              \
    _Pragma("unroll")                                                         \
    for (int kfm = 0; kfm < 4; ++kfm)                                         \
      kq[kfm] = *(const f32x4*)&KQs[c_ * 64 + kfm * 16 + q4 * 4];             \
    bf16x8 pf[2][2];                                                          \
    _Pragma("unroll")                                                         \
    for (int qg = 0; qg < 2; ++qg) {                                          \
      _Pragma("unroll")                                                       \
      for (int cb = 0; cb < 2; ++cb) {                                        \
        unsigned int dw[4];                                                   \
        _Pragma("unroll")                                                     \
        for (int half = 0; half < 2; ++half) {                                \
          int kfm = cb * 2 + half;                                            \
          float pp[4];                                                        \
          _Pragma("unroll")                                                   \
          for (int i = 0; i < 4; ++i) {                                       \
            float u = __builtin_fmaf(cc, st[qg][kfm][i], -kq[kfm][i]);        \
            pp[i] = __builtin_amdgcn_exp2f(u);                                \
          }                                                                   \
          dw[half * 2 + 0] = (fbits(pp[0]) >> 16) | (fbits(pp[1]) & 0xFFFF0000u); \
          dw[half * 2 + 1] = (fbits(pp[2]) >> 16) | (fbits(pp[3]) & 0xFFFF0000u); \
        }                                                                     \
        union { unsigned int d[4]; bf16x8 v; } cv;                            \
        cv.d[0] = dw[0]; cv.d[1] = dw[1]; cv.d[2] = dw[2]; cv.d[3] = dw[3];   \
        pf[qg][cb] = cv.v;                                                    \
      }                                                                       \
    }                                                                         \
    /* PV(c): O += P.V ; lsum += P.ones */                                    \
    __builtin_amdgcn_s_setprio(1);                                            \
    _Pragma("unroll")                                                         \
    for (int cb = 0; cb < 2; ++cb) {                                          \
      lsum[0] = __builtin_amdgcn_mfma_f32_16x16x32_bf16(pf[0][cb], ones, lsum[0], 0, 0, 0); \
      lsum[1] = __builtin_amdgcn_mfma_f32_16x16x32_bf16(pf[1][cb], ones, lsum[1], 0, 0, 0); \
      _Pragma("unroll")                                                       \
      for (int df = 0; df < 4; ++df) {                                        \
        int dloc = df * 16 + r;                                               \
        int un = dloc * 8 + ((cb * 4 + q4) ^ (dloc & 7));                     \
        bf16x8 vb = *(const bf16x8*)&Vs[(J)][un * 8];                         \
        accO[0][df] = __builtin_amdgcn_mfma_f32_16x16x32_bf16(pf[0][cb], vb, accO[0][df], 0, 0, 0); \
        accO[1][df] = __builtin_amdgcn_mfma_f32_16x16x32_bf16(pf[1][cb], vb, accO[1][df], 0, 0, 0); \
      }                                                                       \
    }                                                                         \
    __builtin_amdgcn_s_setprio(0);                                            \
    /* drain the in-flight stage (full body of cover), publish */             \
    if (!(LAST)) {                                                            \
      asm volatile("s_waitcnt vmcnt(0)" ::: "memory");                        \
      __builtin_amdgcn_s_barrier();                                           \
      __builtin_amdgcn_sched_barrier(0);                                      \
    }                                                                         \
  }

  CHUNK_BODY(0, 0, 0, 0)                // chunk1 already staged in prologue
  for (int c2 = 0; c2 < 15; ++c2) {     // c = 1..30: stage c+1 into J^1
    CHUNK_BODY(2 * c2 + 1, 1, 1, 0)
    CHUNK_BODY(2 * c2 + 2, 0, 1, 0)
  }
  CHUNK_BODY(31, 1, 0, 1)               // last
#undef CHUNK_BODY
#undef STAGE_CHUNK

  {
    #pragma unroll
    for (int qg = 0; qg < 2; ++qg) {
      float inv[4];
      #pragma unroll
      for (int i = 0; i < 4; ++i) inv[i] = 1.0f / lsum[qg][i];
      #pragma unroll
      for (int df = 0; df < 4; ++df) {
        int d = df * 16 + r;
        #pragma unroll
        for (int i = 0; i < 4; ++i) {
          int sq = q0 + w * 32 + qg * 16 + q4 * 4 + i;
          AO[(size_t)(b * 2048 + sq) * 1024 + h * 64 + d] = f2b(accO[qg][df][i] * inv[i]);
        }
      }
    }
  }
}

// ------------------------------------------------------------- out GEMM
// 128x64 tile, BK=32 half-steps, 3-buffer 2-deep pipeline, 1 barrier +
// vmcnt(3) per half-step, grid 16x32 = 512 blocks (2/CU).
// LDS tiles XOR-unit swizzled (same scheme as qkv).
__global__ __launch_bounds__(256, 2) void gemm_out_kernel(
    const unsigned short* __restrict__ A, const unsigned short* __restrict__ WT,
    const float* __restrict__ bo, float* __restrict__ Out) {
  __shared__ __align__(16) unsigned short osmem[18432];  // A3(12288) B3(6144)
#define AS3o(j) (osmem + (j) * 4096)
#define BS3o(j) (osmem + 12288 + (j) * 2048)
  const int t = threadIdx.x, w = t >> 6, lane = t & 63;
  const int r = lane & 15, q4 = lane >> 4;
  const int m0 = blockIdx.y * 128, n0 = blockIdx.x * 64;
  const int wr = (w >> 1) * 64, wc = (w & 1) * 32;
  const unsigned short* Ag = A + (size_t)m0 * 1024;
  const unsigned short* Wg = WT + (size_t)n0 * 1024;
  const int swz = ((t & 3) ^ ((t >> 2) & 3)) * 8;
  const unsigned short* as0 = Ag + (size_t)(t >> 2) * 1024 + swz;
  const unsigned short* as1 = as0 + (size_t)64 * 1024;
  const unsigned short* bs0 = Wg + (size_t)(t >> 2) * 1024 + swz;
  f32x4 acc[4][2] = {};

#define OUT_STAGE(J2)                                     \
  {                                                       \
    GLD_LDS(as0, &AS3o(J2)[(w * 64) * 8]);                \
    GLD_LDS(as1, &AS3o(J2)[(256 + w * 64) * 8]);          \
    GLD_LDS(bs0, &BS3o(J2)[(w * 64) * 8]);                \
    as0 += 32; as1 += 32; bs0 += 32;                      \
  }

  OUT_STAGE(0)
  OUT_STAGE(1)
  asm volatile("s_waitcnt vmcnt(3)" ::: "memory");
  __builtin_amdgcn_s_barrier();
  __builtin_amdgcn_sched_barrier(0);

  const int ru = (q4 ^ (r & 3)) * 8;    // swizzled read unit offset

#define OUT_BODY(J, STG, LAST)                                                \
  {                                                                           \
    if (STG) OUT_STAGE(((J) + 2) % 3)                                         \
    bf16x8 af[4], bfr[2];                                                     \
    _Pragma("unroll")                                                         \
    for (int mf = 0; mf < 4; ++mf)                                            \
      af[mf] = *(const bf16x8*)&AS3o(J)[(wr + mf * 16 + r) * 32 + ru];        \
    _Pragma("unroll")                                                         \
    for (int nf = 0; nf < 2; ++nf)                                            \
      bfr[nf] = *(const bf16x8*)&BS3o(J)[(wc + nf * 16 + r) * 32 + ru];       \
    _Pragma("unroll")                                                         \
    for (int mf = 0; mf < 4; ++mf)                                            \
      _Pragma("unroll")                                                       \
      for (int nf = 0; nf < 2; ++nf)                                          \
        acc[mf][nf] = __builtin_amdgcn_mfma_f32_16x16x32_bf16(af[mf], bfr[nf], acc[mf][nf], 0, 0, 0); \
    if (STG)       { asm volatile("s_waitcnt vmcnt(3)" ::: "memory"); }       \
    else if (!(LAST)) { asm volatile("s_waitcnt vmcnt(0)" ::: "memory"); }    \
    if (!(LAST)) {                                                            \
      __builtin_amdgcn_s_barrier();                                           \
      __builtin_amdgcn_sched_barrier(0);                                      \
    }                                                                         \
  }

  for (int hh = 0; hh < 5; ++hh) {
    OUT_BODY(0, 1, 0) OUT_BODY(1, 1, 0) OUT_BODY(2, 1, 0)
    OUT_BODY(0, 1, 0) OUT_BODY(1, 1, 0) OUT_BODY(2, 1, 0)
  }
  OUT_BODY(0, 0, 0)
  OUT_BODY(1, 0, 1)
#undef OUT_BODY
#undef OUT_STAGE
#undef AS3o
#undef BS3o

  #pragma unroll
  for (int nf = 0; nf < 2; ++nf) {
    int n = n0 + wc + nf * 16 + r;
    float bb = bo[n];
    #pragma unroll
    for (int mf = 0; mf < 4; ++mf) {
      int m = m0 + wr + mf * 16 + q4 * 4;
      f32x4 v = acc[mf][nf];
      #pragma unroll
      for (int i = 0; i < 4; ++i)
        Out[(size_t)(m + i) * 1024 + n] = v[i] + bb;
    }
  }
}

// ---------------------------------------------------------------- launch
extern "C" void kernel_launch(void* const* d_in, const int* in_sizes, int n_in,
                              void* d_out, int out_size, void* d_ws, size_t ws_size,
                              hipStream_t stream) {
  const float* X    = (const float*)d_in[0];
  const float* wq   = (const float*)d_in[1];
  const float* bq   = (const float*)d_in[2];
  const float* wk   = (const float*)d_in[3];
  const float* bk   = (const float*)d_in[4];
  const float* wv   = (const float*)d_in[5];
  const float* bv   = (const float*)d_in[6];
  const float* wo   = (const float*)d_in[7];
  const float* bo   = (const float*)d_in[8];
  const float* temp = (const float*)d_in[9];
  float* Out = (float*)d_out;

  char* ws = (char*)d_ws;
  unsigned short* Xb    = (unsigned short*)ws; ws += (size_t)4096 * 1024 * 2;
  unsigned short* WTqkv = (unsigned short*)ws; ws += (size_t)3072 * 1024 * 2;
  unsigned short* WTo   = (unsigned short*)ws; ws += (size_t)1024 * 1024 * 2;
  unsigned short* Qb    = (unsigned short*)ws; ws += (size_t)4096 * 1024 * 2;
  unsigned short* Kb    = (unsigned short*)ws; ws += (size_t)4096 * 1024 * 2;
  unsigned short* VT    = (unsigned short*)ws; ws += (size_t)4096 * 1024 * 2;
  float* ks2 = (float*)ws; ws += (size_t)65536 * 4;
  unsigned short* AO = Xb;   // Xb dead after gemm_qkv; reuse for flash output

  prep_kernel<<<dim3(16, 16, 5), 256, 0, stream>>>(X, wq, wk, wv, wo, Xb, WTqkv, WTo);
  gemm_qkv_kernel<<<dim3(24, 32), 256, 0, stream>>>(Xb, WTqkv, bq, bk, bv, temp, Qb, Kb, VT, ks2);
  flash_kernel<<<dim3(32, 32), 128, 0, stream>>>(Qb, Kb, VT, ks2, temp, AO);
  gemm_out_kernel<<<dim3(16, 32), 256, 0, stream>>>(AO, WTo, bo, Out);
}

// Round 12
// 185.932 us; speedup vs baseline: 1.0057x; 1.0057x over previous
//
#include <hip/hip_runtime.h>
#include <stdint.h>
#include <stddef.h>

// EuclideanAttention MI355X, round 21.
// - flash: REVERT to r17/r19 (256-thread, 128 q-rows, K[3]/V[3], single
//   barrier + counted vmcnt(4), 2 blocks/CU). r20's 4-domain/128-thread
//   variant regressed to 60.8 (double-buffer forces stage-distance 1 ->
//   vmcnt(0) per chunk kills latency tolerance). Flash design space now
//   fully mapped: 1bl=56, 2bl@256=50 (optimum), 4bl@128=61, 4bl@2xtraffic=61.
// - GEMMs + prep: identical to r19/r20 (controls).

#define LOG2E 1.44269504088896f

typedef __attribute__((ext_vector_type(8))) short bf16x8;
typedef __attribute__((ext_vector_type(4))) float f32x4;
typedef __attribute__((ext_vector_type(4))) unsigned short u16x4;

__device__ __forceinline__ unsigned short f2b(float f) {
  union { float f; unsigned int u; } x; x.f = f;
  unsigned int u = x.u;
  u += 0x7fffu + ((u >> 16) & 1u);   // RNE
  return (unsigned short)(u >> 16);
}
__device__ __forceinline__ float b2f(unsigned short s) {
  union { unsigned int u; float f; } x; x.u = ((unsigned int)s) << 16;
  return x.f;
}
__device__ __forceinline__ unsigned int fbits(float f) {
  union { float f; unsigned int u; } x; x.f = f; return x.u;
}

// async global->LDS, 16B per lane. LDS dest = wave-uniform base + lane*16.
#define GLD_LDS(g, l) __builtin_amdgcn_global_load_lds( \
    (const __attribute__((address_space(1))) void*)(g), \
    (__attribute__((address_space(3))) void*)(l), 16, 0, 0)

// ------------------------------------------------- prep: W transpose + X cvt
__global__ void prep_kernel(const float* __restrict__ X,
                            const float* __restrict__ wq, const float* __restrict__ wk,
                            const float* __restrict__ wv, const float* __restrict__ wo,
                            unsigned short* __restrict__ Xb,
                            unsigned short* __restrict__ WTqkv, unsigned short* __restrict__ WTo) {
  int z = blockIdx.z;
  if (z == 4) {
    size_t base = ((size_t)(blockIdx.y * 16 + blockIdx.x)) * 16384;
    #pragma unroll
    for (int j = 0; j < 16; ++j) {
      size_t i = base + (size_t)(j * 256 + threadIdx.x) * 4;
      f32x4 v = *(const f32x4*)&X[i];
      u16x4 o;
      #pragma unroll
      for (int k = 0; k < 4; ++k) o[k] = f2b(v[k]);
      *(u16x4*)&Xb[i] = o;
    }
    return;
  }
  __shared__ float tile[64][65];
  const float* src = (z == 0) ? wq : (z == 1) ? wk : (z == 2) ? wv : wo;
  unsigned short* dst = (z < 3) ? (WTqkv + (size_t)z * 1024 * 1024) : WTo;
  int k0 = blockIdx.y * 64, n0 = blockIdx.x * 64;
  int tr = threadIdx.x >> 4;           // 0..15
  int tc4 = (threadIdx.x & 15) * 4;    // 0,4,..,60
  #pragma unroll
  for (int p = 0; p < 4; ++p) {
    int row = p * 16 + tr;
    f32x4 v = *(const f32x4*)&src[(size_t)(k0 + row) * 1024 + n0 + tc4];
    #pragma unroll
    for (int j = 0; j < 4; ++j) tile[row][tc4 + j] = v[j];
  }
  __syncthreads();
  #pragma unroll
  for (int p = 0; p < 4; ++p) {
    int nr = p * 16 + tr;              // n offset
    u16x4 o;
    #pragma unroll
    for (int j = 0; j < 4; ++j) o[j] = f2b(tile[tc4 + j][nr]);
    *(u16x4*)&dst[(size_t)(n0 + nr) * 1024 + k0 + tc4] = o;
  }
}

// -------------------------------------------------------------- QKV GEMM
// C[4096,3072] = X @ [wq|wk|wv] + bias. 128x128 tile, BK=32 half-steps,
// 3-buffer 2-deep pipeline, 1 barrier + vmcnt(4) per half-step, 3 blocks/CU.
// LDS tiles XOR-unit swizzled: unit' = ko ^ (row&3)  (bank 8-way -> 4-way).
__global__ __launch_bounds__(256, 3) void gemm_qkv_kernel(
    const unsigned short* __restrict__ X, const unsigned short* __restrict__ WT,
    const float* __restrict__ bq, const float* __restrict__ bk, const float* __restrict__ bv,
    const float* __restrict__ temp,
    unsigned short* __restrict__ Qb, unsigned short* __restrict__ Kb,
    unsigned short* __restrict__ VTo, float* __restrict__ ks2) {
  __shared__ __align__(16) unsigned short smem3[24576];  // A3(12288) B3(12288) | Vt alias
#define AS3(j) (smem3 + (j) * 4096)
#define BS3(j) (smem3 + 12288 + (j) * 4096)
  const int t = threadIdx.x, w = t >> 6, lane = t & 63;
  const int r = lane & 15, q4 = lane >> 4;
  const int m0 = blockIdx.y * 128, n0 = blockIdx.x * 128;
  const int wr = (w >> 1) * 64, wc = (w & 1) * 64;
  const unsigned short* Xg = X + (size_t)m0 * 1024;
  const unsigned short* Wg = WT + (size_t)n0 * 1024;
  const int swz = ((t & 3) ^ ((t >> 2) & 3)) * 8;
  const unsigned short* xs0 = Xg + (size_t)(t >> 2) * 1024 + swz;
  const unsigned short* xs1 = xs0 + (size_t)64 * 1024;
  const unsigned short* ws0 = Wg + (size_t)(t >> 2) * 1024 + swz;
  const unsigned short* ws1 = ws0 + (size_t)64 * 1024;
  f32x4 acc[4][4] = {};

#define QKV_STAGE(J2)                                     \
  {                                                       \
    GLD_LDS(xs0, &AS3(J2)[(w * 64) * 8]);                 \
    GLD_LDS(xs1, &AS3(J2)[(256 + w * 64) * 8]);           \
    GLD_LDS(ws0, &BS3(J2)[(w * 64) * 8]);                 \
    GLD_LDS(ws1, &BS3(J2)[(256 + w * 64) * 8]);           \
    xs0 += 32; xs1 += 32; ws0 += 32; ws1 += 32;           \
  }

  QKV_STAGE(0)
  QKV_STAGE(1)
  asm volatile("s_waitcnt vmcnt(4)" ::: "memory");
  __builtin_amdgcn_s_barrier();
  __builtin_amdgcn_sched_barrier(0);

  const int ru = (q4 ^ (r & 3)) * 8;    // swizzled read unit offset (bf16 elems)

#define QKV_BODY(J, STG, LAST)                                                \
  {                                                                           \
    if (STG) QKV_STAGE(((J) + 2) % 3)                                         \
    bf16x8 af[4], bfr[4];                                                     \
    _Pragma("unroll")                                                         \
    for (int mf = 0; mf < 4; ++mf)                                            \
      af[mf] = *(const bf16x8*)&AS3(J)[(wr + mf * 16 + r) * 32 + ru];         \
    _Pragma("unroll")                                                         \
    for (int nf = 0; nf < 4; ++nf)                                            \
      bfr[nf] = *(const bf16x8*)&BS3(J)[(wc + nf * 16 + r) * 32 + ru];        \
    _Pragma("unroll")                                                         \
    for (int mf = 0; mf < 4; ++mf)                                            \
      _Pragma("unroll")                                                       \
      for (int nf = 0; nf < 4; ++nf)                                          \
        acc[mf][nf] = __builtin_amdgcn_mfma_f32_16x16x32_bf16(af[mf], bfr[nf], acc[mf][nf], 0, 0, 0); \
    if (STG)       { asm volatile("s_waitcnt vmcnt(4)" ::: "memory"); }       \
    else if (!(LAST)) { asm volatile("s_waitcnt vmcnt(0)" ::: "memory"); }    \
    if (!(LAST)) {                                                            \
      __builtin_amdgcn_s_barrier();                                           \
      __builtin_amdgcn_sched_barrier(0);                                      \
    }                                                                         \
  }

  for (int hh = 0; hh < 5; ++hh) {
    QKV_BODY(0, 1, 0) QKV_BODY(1, 1, 0) QKV_BODY(2, 1, 0)
    QKV_BODY(0, 1, 0) QKV_BODY(1, 1, 0) QKV_BODY(2, 1, 0)
  }
  QKV_BODY(0, 0, 0)
  QKV_BODY(1, 0, 1)
  __syncthreads();
#undef QKV_BODY
#undef QKV_STAGE

  const int nblk = n0 >> 10;
  if (nblk == 0) {
    const int nc0 = n0 & 1023;
    #pragma unroll
    for (int nf = 0; nf < 4; ++nf) {
      int n = nc0 + wc + nf * 16 + r;
      float bb = bq[n];
      #pragma unroll
      for (int mf = 0; mf < 4; ++mf) {
        int m = m0 + wr + mf * 16 + q4 * 4;
        f32x4 v = acc[mf][nf];
        #pragma unroll
        for (int i = 0; i < 4; ++i)
          Qb[(size_t)(m + i) * 1024 + n] = f2b(v[i] + bb);
      }
    }
  } else if (nblk == 1) {
    const float sc = LOG2E / temp[0];
    const int nc0 = n0 & 1023;
    float s2a[4][4] = {};
    #pragma unroll
    for (int nf = 0; nf < 4; ++nf) {
      int n = nc0 + wc + nf * 16 + r;
      float bb = bk[n];
      #pragma unroll
      for (int mf = 0; mf < 4; ++mf) {
        int m = m0 + wr + mf * 16 + q4 * 4;
        f32x4 v = acc[mf][nf];
        #pragma unroll
        for (int i = 0; i < 4; ++i) {
          unsigned short os = f2b(v[i] + bb);
          Kb[(size_t)(m + i) * 1024 + n] = os;
          float xb = b2f(os);
          s2a[mf][i] += xb * xb;          // sum of squares of the ROUNDED value
        }
      }
    }
    #pragma unroll
    for (int mf = 0; mf < 4; ++mf)
      #pragma unroll
      for (int i = 0; i < 4; ++i) {
        float v = s2a[mf][i];
        v += __shfl_xor(v, 1, 64);
        v += __shfl_xor(v, 2, 64);
        v += __shfl_xor(v, 4, 64);
        v += __shfl_xor(v, 8, 64);
        s2a[mf][i] = v * sc;
      }
    if (r == 0) {
      int hh2 = (nc0 + wc) >> 6;
      #pragma unroll
      for (int mf = 0; mf < 4; ++mf) {
        int m = m0 + wr + mf * 16 + q4 * 4;
        int bb2 = m >> 11, ss = m & 2047;
        #pragma unroll
        for (int i = 0; i < 4; ++i)
          ks2[(size_t)(bb2 * 16 + hh2) * 2048 + ss + i] = s2a[mf][i];
      }
    }
  } else {
    unsigned short* Vt = smem3;         // [head<2][d<64][G<2 * pos<64], stride 132
    const int c0 = n0 - 2048;
    const int head = w & 1;
    #pragma unroll
    for (int nf = 0; nf < 4; ++nf) {
      int c = c0 + wc + nf * 16 + r;
      float bb = bv[c];
      int d = c & 63;
      #pragma unroll
      for (int mf = 0; mf < 4; ++mf) {
        int mloc = wr + mf * 16 + q4 * 4;     // 0..124
        int G = mloc >> 6;
        int k6 = mloc & 63;
        int pos = (k6 >> 5) * 32 + ((k6 & 15) >> 2) * 8 + ((k6 >> 4) & 1) * 4;
        f32x4 v = acc[mf][nf];
        u16x4 pk;
        #pragma unroll
        for (int i = 0; i < 4; ++i) pk[i] = f2b(v[i] + bb);
        *(u16x4*)&Vt[(head * 64 + d) * 132 + G * 64 + pos] = pk;
      }
    }
    __syncthreads();
    int row = t >> 1, ch = t & 1;
    int hd = row >> 6, dd = row & 63;
    int hglob = (c0 >> 6) + hd;
    int bb2 = m0 >> 11, s0 = m0 & 2047;
    unsigned short* dst = &VTo[((size_t)((bb2 * 16 + hglob) * 64 + dd)) * 2048 + s0 + ch * 64];
    const unsigned short* srcL = &Vt[(hd * 64 + dd) * 132 + ch * 64];
    #pragma unroll
    for (int k2 = 0; k2 < 16; ++k2)
      *(u16x4*)&dst[k2 * 4] = *(const u16x4*)&srcL[k2 * 4];
  }
#undef AS3
#undef BS3
}

// ---------------------------------------------------------------- flash
// r17/r19 (proven ~50us): Block = (bh, 128 q-rows), 4 waves x 32 rows.
// Grid 512, XCD-swizzled (bh == wgid mod 8; per-XCD KV 2MB L2-resident).
// 64-key chunks, K[3]/V[3], ONE barrier per chunk, counted vmcnt(4).
// p = exp2((2qk - k^2)*log2e/T)  (q^2 shift cancels; bounded by ~8)
__global__ __launch_bounds__(256, 2) void flash_kernel(
    const unsigned short* __restrict__ Qb, const unsigned short* __restrict__ Kb,
    const unsigned short* __restrict__ VT, const float* __restrict__ ks2,
    const float* __restrict__ temp, unsigned short* __restrict__ AO) {
  __shared__ __align__(16) unsigned short Ks[3][64 * 64];   // [buf][khalf<2][key<64][dd<32]
  __shared__ __align__(16) unsigned short Vs[3][64 * 64];   // [buf] XOR-swizzled 16B units
  __shared__ __align__(16) float KQs[2048];                 // pre-scaled k^2 for this bh
  const int t = threadIdx.x, w = t >> 6, lane = t & 63;
  const int r = lane & 15, q4 = lane >> 4;
  const int wgid = blockIdx.x + 16 * blockIdx.y;   // [0,512)
  const int xcd = wgid & 7, s = wgid >> 3;         // s in [0,64)
  const int bh = xcd + 8 * (s & 3);                // 4 bh per XCD
  const int b = bh >> 4, h = bh & 15;
  const int q0 = (s >> 2) * 128;                   // 16 q-chunks per bh
  const float cc = 2.0f * LOG2E / temp[0];

  bf16x8 qf[2][2];
  #pragma unroll
  for (int qg = 0; qg < 2; ++qg) {
    int sq = q0 + w * 32 + qg * 16 + r;
    const unsigned short* qp = Qb + (size_t)(b * 2048 + sq) * 1024 + h * 64;
    #pragma unroll
    for (int ks = 0; ks < 2; ++ks) qf[qg][ks] = *(const bf16x8*)(qp + ks * 32 + q4 * 8);
  }

  f32x4 accO[2][4] = {};
  f32x4 lsum[2] = {};
  bf16x8 ones;
  #pragma unroll
  for (int j = 0; j < 8; ++j) ones[j] = (short)0x3F80;   // bf16 1.0

  const unsigned short* Kg = Kb + ((size_t)b * 2048) * 1024 + h * 64;
  const unsigned short* Vg = VT + ((size_t)bh * 64) * 2048;
  const float* kqb = ks2 + bh * 2048;

  const unsigned short* kp0 = Kg + (size_t)(t >> 2) * 1024 + (t & 3) * 8;  // khalf 0
  const unsigned short* kp1 = kp0 + 32;                                    // khalf 1
  int dd0 = t >> 3;
  const unsigned short* vp0 = Vg + (size_t)dd0 * 2048 + ((t & 7) ^ (dd0 & 7)) * 8;
  const unsigned short* vp1 = vp0 + (size_t)32 * 2048;

  // ---- prologue: ks2 -> LDS, stage chunk0 -> buf0, chunk1 -> buf1
  GLD_LDS(kqb + t * 4, &KQs[t * 4]);
  GLD_LDS(kqb + 1024 + t * 4, &KQs[1024 + t * 4]);
  GLD_LDS(kp0, &Ks[0][t * 8]);
  GLD_LDS(kp1, &Ks[0][(256 + t) * 8]);
  GLD_LDS(vp0, &Vs[0][t * 8]);
  GLD_LDS(vp1, &Vs[0][(256 + t) * 8]);
  kp0 += 65536; kp1 += 65536; vp0 += 64; vp1 += 64;
  GLD_LDS(kp0, &Ks[1][t * 8]);
  GLD_LDS(kp1, &Ks[1][(256 + t) * 8]);
  GLD_LDS(vp0, &Vs[1][t * 8]);
  GLD_LDS(vp1, &Vs[1][(256 + t) * 8]);
  kp0 += 65536; kp1 += 65536; vp0 += 64; vp1 += 64;
  // drain qf + ks2 + stage0 (leaves stage1's 4 in flight)
  asm volatile("s_waitcnt vmcnt(4)" ::: "memory");
  __builtin_amdgcn_s_barrier();
  __builtin_amdgcn_sched_barrier(0);

  // ---- main loop, ONE barrier per chunk. J = c%3 static per body.
#define CHUNK_BODY(C, J, STG, LAST)                                           \
  {                                                                           \
    const int c_ = (C);                                                       \
    if (STG) {                                                                \
      GLD_LDS(kp0, &Ks[((J) + 2) % 3][t * 8]);                                \
      GLD_LDS(kp1, &Ks[((J) + 2) % 3][(256 + t) * 8]);                        \
      GLD_LDS(vp0, &Vs[((J) + 2) % 3][t * 8]);                                \
      GLD_LDS(vp1, &Vs[((J) + 2) % 3][(256 + t) * 8]);                        \
      kp0 += 65536; kp1 += 65536; vp0 += 64; vp1 += 64;                       \
    }                                                                         \
    /* QK(c): A=K-frag (m=key), B=Q-frag (n=qrow); 2 MFMAs per K read */      \
    f32x4 st[2][4];                                                           \
    {                                                                         \
      const f32x4 zz = {};                                                    \
      __builtin_amdgcn_s_setprio(1);                                          \
      _Pragma("unroll")                                                       \
      for (int ks = 0; ks < 2; ++ks) {                                        \
        _Pragma("unroll")                                                     \
        for (int kfm = 0; kfm < 4; ++kfm) {                                   \
          bf16x8 ka = *(const bf16x8*)&Ks[(J)][(ks * 64 + kfm * 16 + r) * 32 + q4 * 8]; \
          st[0][kfm] = __builtin_amdgcn_mfma_f32_16x16x32_bf16(ka, qf[0][ks], ks ? st[0][kfm] : zz, 0, 0, 0); \
          st[1][kfm] = __builtin_amdgcn_mfma_f32_16x16x32_bf16(ka, qf[1][ks], ks ? st[1][kfm] : zz, 0, 0, 0); \
        }                                                                     \
      }                                                                       \
      __builtin_amdgcn_s_setprio(0);                                          \
    }                                                                         \
    /* exp(c): p = exp2(cc*qk - k2s); trunc-pack to pf[qg][cb] */             \
    f32x4 kq[4];                                                              \
    _Pragma("unroll")                                                         \
    for (int kfm = 0; kfm < 4; ++kfm)                                         \
      kq[kfm] = *(const f32x4*)&KQs[c_ * 64 + kfm * 16 + q4 * 4];             \
    bf16x8 pf[2][2];                                                          \
    _Pragma("unroll")                                                         \
    for (int qg = 0; qg < 2; ++qg) {                                          \
      _Pragma("unroll")                                                       \
      for (int cb = 0; cb < 2; ++cb) {                                        \
        unsigned int dw[4];                                                   \
        _Pragma("unroll")                                                     \
        for (int half = 0; half < 2; ++half) {                                \
          int kfm = cb * 2 + half;                                            \
          float pp[4];                                                        \
          _Pragma("unroll")                                                   \
          for (int i = 0; i < 4; ++i) {                                       \
            float u = __builtin_fmaf(cc, st[qg][kfm][i], -kq[kfm][i]);        \
            pp[i] = __builtin_amdgcn_exp2f(u);                                \
          }                                                                   \
          dw[half * 2 + 0] = (fbits(pp[0]) >> 16) | (fbits(pp[1]) & 0xFFFF0000u); \
          dw[half * 2 + 1] = (fbits(pp[2]) >> 16) | (fbits(pp[3]) & 0xFFFF0000u); \
        }                                                                     \
        union { unsigned int d[4]; bf16x8 v; } cv;                            \
        cv.d[0] = dw[0]; cv.d[1] = dw[1]; cv.d[2] = dw[2]; cv.d[3] = dw[3];   \
        pf[qg][cb] = cv.v;                                                    \
      }                                                                       \
    }                                                                         \
    /* PV(c): O += P.V ; lsum += P.ones */                                    \
    __builtin_amdgcn_s_setprio(1);                                            \
    _Pragma("unroll")                                                         \
    for (int cb = 0; cb < 2; ++cb) {                                          \
      lsum[0] = __builtin_amdgcn_mfma_f32_16x16x32_bf16(pf[0][cb], ones, lsum[0], 0, 0, 0); \
      lsum[1] = __builtin_amdgcn_mfma_f32_16x16x32_bf16(pf[1][cb], ones, lsum[1], 0, 0, 0); \
      _Pragma("unroll")                                                       \
      for (int df = 0; df < 4; ++df) {                                        \
        int dloc = df * 16 + r;                                               \
        int un = dloc * 8 + ((cb * 4 + q4) ^ (dloc & 7));                     \
        bf16x8 vb = *(const bf16x8*)&Vs[(J)][un * 8];                         \
        accO[0][df] = __builtin_amdgcn_mfma_f32_16x16x32_bf16(pf[0][cb], vb, accO[0][df], 0, 0, 0); \
        accO[1][df] = __builtin_amdgcn_mfma_f32_16x16x32_bf16(pf[1][cb], vb, accO[1][df], 0, 0, 0); \
      }                                                                       \
    }                                                                         \
    __builtin_amdgcn_s_setprio(0);                                            \
    /* drain stage(c+1); keep stage(c+2) in flight */                         \
    if (STG)          { asm volatile("s_waitcnt vmcnt(4)" ::: "memory"); }    \
    else if (!(LAST)) { asm volatile("s_waitcnt vmcnt(0)" ::: "memory"); }    \
    if (!(LAST)) {                                                            \
      __builtin_amdgcn_s_barrier();                                           \
      __builtin_amdgcn_sched_barrier(0);                                      \
    }                                                                         \
  }

  for (int c3 = 0; c3 < 10; ++c3) {     // c = 0..29, all staging
    CHUNK_BODY(3 * c3 + 0, 0, 1, 0)
    CHUNK_BODY(3 * c3 + 1, 1, 1, 0)
    CHUNK_BODY(3 * c3 + 2, 2, 1, 0)
  }
  CHUNK_BODY(30, 0, 0, 0)               // drain st(31)
  CHUNK_BODY(31, 1, 0, 1)               // last
#undef CHUNK_BODY

  {
    #pragma unroll
    for (int qg = 0; qg < 2; ++qg) {
      float inv[4];
      #pragma unroll
      for (int i = 0; i < 4; ++i) inv[i] = 1.0f / lsum[qg][i];
      #pragma unroll
      for (int df = 0; df < 4; ++df) {
        int d = df * 16 + r;
        #pragma unroll
        for (int i = 0; i < 4; ++i) {
          int sq = q0 + w * 32 + qg * 16 + q4 * 4 + i;
          AO[(size_t)(b * 2048 + sq) * 1024 + h * 64 + d] = f2b(accO[qg][df][i] * inv[i]);
        }
      }
    }
  }
}

// ------------------------------------------------------------- out GEMM
// 128x64 tile, BK=32 half-steps, 3-buffer 2-deep pipeline, 1 barrier +
// vmcnt(3) per half-step, grid 16x32 = 512 blocks (2/CU).
// LDS tiles XOR-unit swizzled (same scheme as qkv).
__global__ __launch_bounds__(256, 2) void gemm_out_kernel(
    const unsigned short* __restrict__ A, const unsigned short* __restrict__ WT,
    const float* __restrict__ bo, float* __restrict__ Out) {
  __shared__ __align__(16) unsigned short osmem[18432];  // A3(12288) B3(6144)
#define AS3o(j) (osmem + (j) * 4096)
#define BS3o(j) (osmem + 12288 + (j) * 2048)
  const int t = threadIdx.x, w = t >> 6, lane = t & 63;
  const int r = lane & 15, q4 = lane >> 4;
  const int m0 = blockIdx.y * 128, n0 = blockIdx.x * 64;
  const int wr = (w >> 1) * 64, wc = (w & 1) * 32;
  const unsigned short* Ag = A + (size_t)m0 * 1024;
  const unsigned short* Wg = WT + (size_t)n0 * 1024;
  const int swz = ((t & 3) ^ ((t >> 2) & 3)) * 8;
  const unsigned short* as0 = Ag + (size_t)(t >> 2) * 1024 + swz;
  const unsigned short* as1 = as0 + (size_t)64 * 1024;
  const unsigned short* bs0 = Wg + (size_t)(t >> 2) * 1024 + swz;
  f32x4 acc[4][2] = {};

#define OUT_STAGE(J2)                                     \
  {                                                       \
    GLD_LDS(as0, &AS3o(J2)[(w * 64) * 8]);                \
    GLD_LDS(as1, &AS3o(J2)[(256 + w * 64) * 8]);          \
    GLD_LDS(bs0, &BS3o(J2)[(w * 64) * 8]);                \
    as0 += 32; as1 += 32; bs0 += 32;                      \
  }

  OUT_STAGE(0)
  OUT_STAGE(1)
  asm volatile("s_waitcnt vmcnt(3)" ::: "memory");
  __builtin_amdgcn_s_barrier();
  __builtin_amdgcn_sched_barrier(0);

  const int ru = (q4 ^ (r & 3)) * 8;    // swizzled read unit offset

#define OUT_BODY(J, STG, LAST)                                                \
  {                                                                           \
    if (STG) OUT_STAGE(((J) + 2) % 3)                                         \
    bf16x8 af[4], bfr[2];                                                     \
    _Pragma("unroll")                                                         \
    for (int mf = 0; mf < 4; ++mf)                                            \
      af[mf] = *(const bf16x8*)&AS3o(J)[(wr + mf * 16 + r) * 32 + ru];        \
    _Pragma("unroll")                                                         \
    for (int nf = 0; nf < 2; ++nf)                                            \
      bfr[nf] = *(const bf16x8*)&BS3o(J)[(wc + nf * 16 + r) * 32 + ru];       \
    _Pragma("unroll")                                                         \
    for (int mf = 0; mf < 4; ++mf)                                            \
      _Pragma("unroll")                                                       \
      for (int nf = 0; nf < 2; ++nf)                                          \
        acc[mf][nf] = __builtin_amdgcn_mfma_f32_16x16x32_bf16(af[mf], bfr[nf], acc[mf][nf], 0, 0, 0); \
    if (STG)       { asm volatile("s_waitcnt vmcnt(3)" ::: "memory"); }       \
    else if (!(LAST)) { asm volatile("s_waitcnt vmcnt(0)" ::: "memory"); }    \
    if (!(LAST)) {                                                            \
      __builtin_amdgcn_s_barrier();                                           \
      __builtin_amdgcn_sched_barrier(0);                                      \
    }                                                                         \
  }

  for (int hh = 0; hh < 5; ++hh) {
    OUT_BODY(0, 1, 0) OUT_BODY(1, 1, 0) OUT_BODY(2, 1, 0)
    OUT_BODY(0, 1, 0) OUT_BODY(1, 1, 0) OUT_BODY(2, 1, 0)
  }
  OUT_BODY(0, 0, 0)
  OUT_BODY(1, 0, 1)
#undef OUT_BODY
#undef OUT_STAGE
#undef AS3o
#undef BS3o

  #pragma unroll
  for (int nf = 0; nf < 2; ++nf) {
    int n = n0 + wc + nf * 16 + r;
    float bb = bo[n];
    #pragma unroll
    for (int mf = 0; mf < 4; ++mf) {
      int m = m0 + wr + mf * 16 + q4 * 4;
      f32x4 v = acc[mf][nf];
      #pragma unroll
      for (int i = 0; i < 4; ++i)
        Out[(size_t)(m + i) * 1024 + n] = v[i] + bb;
    }
  }
}

// ---------------------------------------------------------------- launch
extern "C" void kernel_launch(void* const* d_in, const int* in_sizes, int n_in,
                              void* d_out, int out_size, void* d_ws, size_t ws_size,
                              hipStream_t stream) {
  const float* X    = (const float*)d_in[0];
  const float* wq   = (const float*)d_in[1];
  const float* bq   = (const float*)d_in[2];
  const float* wk   = (const float*)d_in[3];
  const float* bk   = (const float*)d_in[4];
  const float* wv   = (const float*)d_in[5];
  const float* bv   = (const float*)d_in[6];
  const float* wo   = (const float*)d_in[7];
  const float* bo   = (const float*)d_in[8];
  const float* temp = (const float*)d_in[9];
  float* Out = (float*)d_out;

  char* ws = (char*)d_ws;
  unsigned short* Xb    = (unsigned short*)ws; ws += (size_t)4096 * 1024 * 2;
  unsigned short* WTqkv = (unsigned short*)ws; ws += (size_t)3072 * 1024 * 2;
  unsigned short* WTo   = (unsigned short*)ws; ws += (size_t)1024 * 1024 * 2;
  unsigned short* Qb    = (unsigned short*)ws; ws += (size_t)4096 * 1024 * 2;
  unsigned short* Kb    = (unsigned short*)ws; ws += (size_t)4096 * 1024 * 2;
  unsigned short* VT    = (unsigned short*)ws; ws += (size_t)4096 * 1024 * 2;
  float* ks2 = (float*)ws; ws += (size_t)65536 * 4;
  unsigned short* AO = Xb;   // Xb dead after gemm_qkv; reuse for flash output

  prep_kernel<<<dim3(16, 16, 5), 256, 0, stream>>>(X, wq, wk, wv, wo, Xb, WTqkv, WTo);
  gemm_qkv_kernel<<<dim3(24, 32), 256, 0, stream>>>(Xb, WTqkv, bq, bk, bv, temp, Qb, Kb, VT, ks2);
  flash_kernel<<<dim3(16, 32), 256, 0, stream>>>(Qb, Kb, VT, ks2, temp, AO);
  gemm_out_kernel<<<dim3(16, 32), 256, 0, stream>>>(AO, WTo, bo, Out);
}